// Round 13
// baseline (138.929 us; speedup 1.0000x reference)
//
#include <hip/hip_runtime.h>
#include <math.h>

#define H     2048
#define NE    64
#define KTOP  8
#define NTOK  16384
#define TOKB  128
#define STEPS 32                       // K-half (1024) / 32

typedef __attribute__((ext_vector_type(8))) __bf16 bf16x8;
typedef __attribute__((ext_vector_type(8))) unsigned short us8;
typedef __attribute__((ext_vector_type(4))) float f32x4;

__device__ __forceinline__ unsigned short f2bf(float f) {
    unsigned u = __builtin_bit_cast(unsigned, f);
    return (unsigned short)((u + 0x7FFFu + ((u >> 16) & 1u)) >> 16);  // RNE
}
__device__ __forceinline__ float bf2f(unsigned short s) {
    return __builtin_bit_cast(float, (unsigned)s << 16);
}

// volatile asm global loads: compiler cannot sink/reorder/drain them.
#define GLOAD_F4(dst, ptr, OFF)                                        \
    asm volatile("global_load_dwordx4 %0, %1, off offset:%2"           \
                 : "=v"(dst) : "v"(ptr), "i"(OFF))
#define WAITV(N)                                                       \
    do { asm volatile("s_waitcnt vmcnt(%0)" :: "i"(N));                \
         __builtin_amdgcn_sched_barrier(0); } while (0)

// ---------------------------------------------------------------------------
// k_prep: W fp32 -> bf16, fragment-linear per 64-col half:
// frag_id = h*256 + k32g*4 + nb ; wbf3[frag_id*512 + ln*8 ..+7] =
//   W[h*64 + nb*16 + (ln&15)][k32g*32 + (ln>>4)*8 ..+7]
// (concat col c = h*64+nb*16+lr: c<64 -> Wt row c, else Wn row c-64)
// ---------------------------------------------------------------------------
__global__ __launch_bounds__(256) void k_prep(const float* __restrict__ Wt,
                                              const float* __restrict__ Wn,
                                              unsigned short* __restrict__ wbf3,
                                              float* __restrict__ sums) {
    const int gid = blockIdx.x * 256 + threadIdx.x;   // 32768 threads
    if (blockIdx.x == 0 && threadIdx.x < 128) sums[threadIdx.x] = 0.f;

    const int ln   = gid & 63;
    const int nb   = (gid >> 6) & 3;
    const int k32g = (gid >> 8) & 63;
    const int h    = (gid >> 14) & 1;
    const int c    = h * 64 + nb * 16 + (ln & 15);
    const int col  = k32g * 32 + (ln >> 4) * 8;
    const float* src = (c < NE) ? (Wt + (size_t)c * H + col)
                                : (Wn + (size_t)(c - NE) * H + col);
    float4 v0 = *(const float4*)src;
    float4 v1 = *(const float4*)(src + 4);
    us8 o;
    o[0] = f2bf(v0.x); o[1] = f2bf(v0.y); o[2] = f2bf(v0.z); o[3] = f2bf(v0.w);
    o[4] = f2bf(v1.x); o[5] = f2bf(v1.y); o[6] = f2bf(v1.z); o[7] = f2bf(v1.w);
    *(us8*)(wbf3 + (size_t)gid * 8) = o;
}

// ---------------------------------------------------------------------------
// k_main: N-split byte-diet. 256 blocks = 128 token-tiles x 2 col-halves.
// Block (tt = blk>>1, h = blk&1): 128 tokens x 64 cols. 8 waves = 4 wm x 2 kp:
// wave = 32 tokens (2 M-frags) x 4 N-frags x K-half [kp*1024,+1024).
// 32 steps of K=32: 8 asm loads (4 B + 4 X), 8 MFMA. Depth-3 slots,
// WAITV(16/8/0), per-block K-rotation s0=(blk>>3)&31 (R12-proven).
// Per-CU gross: X 1.0 MB + B 0.5 MB = 1.5 MB (vs R12's 2.5).
// Epilogue: 2-way kp-combine in LDS -> logits stored bf16 to global.
// ---------------------------------------------------------------------------
__global__ __launch_bounds__(512, 2) void k_main(const float* __restrict__ X,
                                                 const unsigned short* __restrict__ wbf3,
                                                 unsigned short* __restrict__ logits) {
    __shared__ float cb[4][2048];     // kp=1 dump per wm: 2mf*4nb*4r x 64 lanes

    const int tid  = threadIdx.x;
    const int wid  = tid >> 6;
    const int lane = tid & 63;
    const int wm   = wid & 3;         // token group (32 tokens)
    const int kp   = wid >> 2;        // K half
    const int lr   = lane & 15;
    const int lg   = lane >> 4;
    const int blk  = blockIdx.x;
    const int tt   = blk >> 1;
    const int h    = blk & 1;
    const int t0   = tt * TOKB;
    const int s0   = (blk >> 3) & 31; // per-block K rotation

    const float* xp0 = X + (size_t)(t0 + wm * 32 + lr) * H + kp * 1024 + lg * 8;
    const float* xp1 = xp0 + (size_t)16 * H;
    const unsigned short* bp0 = wbf3 + ((size_t)h * 256 + (size_t)kp * 128) * 512
                                     + (size_t)lane * 8;

    f32x4 acc[2][4];
    #pragma unroll
    for (int m = 0; m < 2; ++m)
        #pragma unroll
        for (int i = 0; i < 4; ++i) acc[m][i] = (f32x4){0.f, 0.f, 0.f, 0.f};

    float4 xb[3][2][2];               // [slot][mf][16B-half]  48 VGPR
    us8    bb[3][4];                  // [slot][nb]            48 VGPR

    // one step: 4 B loads then 4 X loads (fixed order; 8 VMEM)
    #define ISSUE(slot, sv)                                                  \
        do {                                                                 \
            const unsigned short* bA = bp0 + (size_t)(sv) * 2048;            \
            GLOAD_F4(bb[slot][0], bA, 0);                                    \
            GLOAD_F4(bb[slot][1], bA, 1024);                                 \
            GLOAD_F4(bb[slot][2], bA, 2048);                                 \
            GLOAD_F4(bb[slot][3], bA, 3072);                                 \
            const float* xA0 = xp0 + (size_t)(sv) * 32;                      \
            const float* xA1 = xp1 + (size_t)(sv) * 32;                      \
            GLOAD_F4(xb[slot][0][0], xA0, 0);                                \
            GLOAD_F4(xb[slot][0][1], xA0, 16);                               \
            GLOAD_F4(xb[slot][1][0], xA1, 0);                                \
            GLOAD_F4(xb[slot][1][1], xA1, 16);                               \
        } while (0)

    ISSUE(0, s0);
    ISSUE(1, (s0 + 1) & 31);
    ISSUE(2, (s0 + 2) & 31);

    #pragma unroll
    for (int j = 0; j < STEPS; ++j) {
        const int slot = j % 3;       // static after unroll
        if (j < STEPS - 2)       WAITV(16);   // step j's 8 oldest done
        else if (j == STEPS - 2) WAITV(8);
        else                     WAITV(0);

        bf16x8 af0, af1;
        {
            float4 c0 = xb[slot][0][0], c1 = xb[slot][0][1];
            af0[0] = (__bf16)c0.x; af0[1] = (__bf16)c0.y;
            af0[2] = (__bf16)c0.z; af0[3] = (__bf16)c0.w;
            af0[4] = (__bf16)c1.x; af0[5] = (__bf16)c1.y;
            af0[6] = (__bf16)c1.z; af0[7] = (__bf16)c1.w;
            float4 d0 = xb[slot][1][0], d1 = xb[slot][1][1];
            af1[0] = (__bf16)d0.x; af1[1] = (__bf16)d0.y;
            af1[2] = (__bf16)d0.z; af1[3] = (__bf16)d0.w;
            af1[4] = (__bf16)d1.x; af1[5] = (__bf16)d1.y;
            af1[6] = (__bf16)d1.z; af1[7] = (__bf16)d1.w;
        }
        #pragma unroll
        for (int nb = 0; nb < 4; ++nb) {
            bf16x8 bfr = __builtin_bit_cast(bf16x8, bb[slot][nb]);
            acc[0][nb] = __builtin_amdgcn_mfma_f32_16x16x32_bf16(af0, bfr, acc[0][nb], 0, 0, 0);
            acc[1][nb] = __builtin_amdgcn_mfma_f32_16x16x32_bf16(af1, bfr, acc[1][nb], 0, 0, 0);
        }
        if (j < STEPS - 3) ISSUE(slot, (s0 + j + 3) & 31);
    }
    #undef ISSUE

    // ---- 2-way kp combine, then bf16 store of logits ----
    if (kp == 1) {
        #pragma unroll
        for (int m = 0; m < 2; ++m)
            #pragma unroll
            for (int nb = 0; nb < 4; ++nb)
                #pragma unroll
                for (int r = 0; r < 4; ++r)
                    cb[wm][((m * 4 + nb) * 4 + r) * 64 + lane] = acc[m][nb][r];
    }
    __syncthreads();
    if (kp == 0) {
        #pragma unroll
        for (int m = 0; m < 2; ++m)
            #pragma unroll
            for (int nb = 0; nb < 4; ++nb)
                #pragma unroll
                for (int r = 0; r < 4; ++r) {
                    float v = acc[m][nb][r] + cb[wm][((m * 4 + nb) * 4 + r) * 64 + lane];
                    int tok = t0 + wm * 32 + m * 16 + lg * 4 + r;
                    int col = h * 64 + nb * 16 + lr;
                    logits[(size_t)tok * 128 + col] = f2bf(v);
                }
    }
}

// ---------------------------------------------------------------------------
// k_topk: per-token gate from bf16 logits -> top-8 -> masked softmax;
// raw per-expert sums via 64-lane butterfly; block-level LDS accumulation.
// 64 blocks x 256 threads, one token per thread.
// ---------------------------------------------------------------------------
__global__ __launch_bounds__(256) void k_topk(const unsigned short* __restrict__ logits,
                                              const float* __restrict__ noise,
                                              float* __restrict__ sumraw,
                                              float* __restrict__ sumsoft) {
    __shared__ float lsoft[NE];
    __shared__ float lraw[NE];
    const int tid = threadIdx.x;
    const int row = blockIdx.x * 256 + tid;

    if (tid < NE) { lsoft[tid] = 0.f; lraw[tid] = 0.f; }
    __syncthreads();

    float g[NE];
    const unsigned short* rp = logits + (size_t)row * 128;
    #pragma unroll
    for (int j = 0; j < 8; ++j) {
        us8 a = *(const us8*)(rp + j * 8);
        us8 b = *(const us8*)(rp + 64 + j * 8);
        #pragma unroll
        for (int q = 0; q < 8; ++q) {
            int e = j * 8 + q;
            float lt  = bf2f(a[q]);
            float lnv = bf2f(b[q]);
            float sp  = fmaxf(lnv, 0.f) + log1pf(expf(-fabsf(lnv)));
            g[e] = lt + sp * noise[e];
        }
    }

    // top-8 (strict > keeps lowest index on ties, matching lax.top_k)
    float tv[KTOP]; int ti[KTOP];
    #pragma unroll
    for (int q = 0; q < KTOP; ++q) { tv[q] = -INFINITY; ti[q] = 0; }
    #pragma unroll
    for (int e = 0; e < NE; ++e) {
        float cv = g[e]; int ci = e;
        #pragma unroll
        for (int q = 0; q < KTOP; ++q) {
            if (cv > tv[q]) {
                float t_ = tv[q]; int i_ = ti[q];
                tv[q] = cv; ti[q] = ci;
                cv = t_; ci = i_;
            }
        }
    }
    float m = tv[0], den = 0.f, pr[KTOP];
    #pragma unroll
    for (int q = 0; q < KTOP; ++q) { pr[q] = expf(tv[q] - m); den += pr[q]; }
    float inv = 1.f / den;
    #pragma unroll
    for (int q = 0; q < KTOP; ++q) atomicAdd(&lsoft[ti[q]], pr[q] * inv);

    // raw sums: butterfly across 64 lanes per expert, lane 0 adds to LDS
    #pragma unroll
    for (int e = 0; e < NE; ++e) {
        float v = g[e];
        v += __shfl_xor(v, 1);  v += __shfl_xor(v, 2);
        v += __shfl_xor(v, 4);  v += __shfl_xor(v, 8);
        v += __shfl_xor(v, 16); v += __shfl_xor(v, 32);
        if ((tid & 63) == 0) atomicAdd(&lraw[e], v);
    }
    __syncthreads();

    if (tid < NE) {
        atomicAdd(&sumraw[tid], lraw[tid]);
        atomicAdd(&sumsoft[tid], lsoft[tid]);
    }
}

// ---------------------------------------------------------------------------
// k_final: mean top-8 + softmax -> out[0..15]; CV^2 -> out[16]
// ---------------------------------------------------------------------------
__global__ void k_final(const float* __restrict__ sumraw,
                        const float* __restrict__ sumsoft,
                        float* __restrict__ out) {
    if (threadIdx.x != 0 || blockIdx.x != 0) return;

    float mw[NE];
    for (int e = 0; e < NE; ++e) mw[e] = sumraw[e] * (1.f / (float)NTOK);

    float tv[KTOP]; int ti[KTOP];
    for (int q = 0; q < KTOP; ++q) { tv[q] = -INFINITY; ti[q] = 0; }
    for (int e = 0; e < NE; ++e) {
        float cv = mw[e]; int ci = e;
        for (int q = 0; q < KTOP; ++q) {
            if (cv > tv[q]) {
                float t_ = tv[q]; int i_ = ti[q];
                tv[q] = cv; ti[q] = ci;
                cv = t_; ci = i_;
            }
        }
    }
    float m = tv[0], den = 0.f, pr[KTOP];
    for (int q = 0; q < KTOP; ++q) { pr[q] = expf(tv[q] - m); den += pr[q]; }
    for (int q = 0; q < KTOP; ++q) {
        out[q] = pr[q] / den;
        out[KTOP + q] = (float)ti[q];
    }

    float s = 0.f;
    for (int e = 0; e < NE; ++e) s += sumsoft[e];
    float mean = s / (float)NE;
    float var = 0.f;
    for (int e = 0; e < NE; ++e) { float d = sumsoft[e] - mean; var += d * d; }
    var /= (float)(NE - 1);  // ddof=1
    out[16] = var / (mean * mean);
}

extern "C" void kernel_launch(void* const* d_in, const int* in_sizes, int n_in,
                              void* d_out, int out_size, void* d_ws, size_t ws_size,
                              hipStream_t stream) {
    (void)in_sizes; (void)n_in; (void)out_size; (void)ws_size;
    const float* x     = (const float*)d_in[0];
    const float* wt    = (const float*)d_in[1];
    const float* wn    = (const float*)d_in[2];
    const float* noise = (const float*)d_in[3];
    float* out = (float*)d_out;

    float* sumraw  = (float*)d_ws;                           // [64]
    float* sumsoft = sumraw + NE;                            // [64]
    unsigned short* wbf3   = (unsigned short*)(sumsoft + NE);     // 512 frags x 512 us = 512 KB
    unsigned short* logits = wbf3 + (size_t)512 * 512;            // [16384][128] bf16 = 4 MB

    k_prep<<<128, 256, 0, stream>>>(wt, wn, wbf3, sumraw);
    k_main<<<256, 512, 0, stream>>>(x, wbf3, logits);
    k_topk<<<64, 256, 0, stream>>>(logits, noise, sumraw, sumsoft);
    k_final<<<1, 64, 0, stream>>>(sumraw, sumsoft, out);
}

// Round 14
// 101.798 us; speedup vs baseline: 1.3648x; 1.3648x over previous
//
#include <hip/hip_runtime.h>
#include <math.h>

#define H     2048
#define NE    64
#define KTOP  8
#define NTOK  16384
#define TOKB  64
#define STEPS 64                       // full K (2048) / 32

typedef __attribute__((ext_vector_type(8))) __bf16 bf16x8;
typedef __attribute__((ext_vector_type(8))) unsigned short us8;
typedef __attribute__((ext_vector_type(4))) float f32x4;

__device__ __forceinline__ unsigned short f2bf(float f) {
    unsigned u = __builtin_bit_cast(unsigned, f);
    return (unsigned short)((u + 0x7FFFu + ((u >> 16) & 1u)) >> 16);  // RNE
}

// volatile asm global loads: compiler cannot sink/reorder/drain them.
#define GLOAD_F4(dst, ptr, OFF)                                        \
    asm volatile("global_load_dwordx4 %0, %1, off offset:%2"           \
                 : "=v"(dst) : "v"(ptr), "i"(OFF))
#define WAITV(N)                                                       \
    do { asm volatile("s_waitcnt vmcnt(%0)" :: "i"(N));                \
         __builtin_amdgcn_sched_barrier(0); } while (0)

// ---------------------------------------------------------------------------
// k_prep: W fp32 -> bf16, fragment-linear (R12 layout):
// wbf2[((k32*8 + nb)*64 + ln)*8 ..] = W[nb*16 + (ln&15)][k32*32 + (ln>>4)*8 ..+7]
// ---------------------------------------------------------------------------
__global__ __launch_bounds__(256) void k_prep(const float* __restrict__ Wt,
                                              const float* __restrict__ Wn,
                                              unsigned short* __restrict__ wbf2,
                                              float* __restrict__ sums) {
    const int gid = blockIdx.x * 256 + threadIdx.x;   // 32768 threads
    if (blockIdx.x == 0 && threadIdx.x < 128) sums[threadIdx.x] = 0.f;

    const int ln  = gid & 63;
    const int nb  = (gid >> 6) & 7;
    const int k32 = gid >> 9;
    const int row = nb * 16 + (ln & 15);
    const int col = k32 * 32 + (ln >> 4) * 8;
    const float* src = (row < NE) ? (Wt + (size_t)row * H + col)
                                  : (Wn + (size_t)(row - NE) * H + col);
    float4 v0 = *(const float4*)src;
    float4 v1 = *(const float4*)(src + 4);
    us8 o;
    o[0] = f2bf(v0.x); o[1] = f2bf(v0.y); o[2] = f2bf(v0.z); o[3] = f2bf(v0.w);
    o[4] = f2bf(v1.x); o[5] = f2bf(v1.y); o[6] = f2bf(v1.z); o[7] = f2bf(v1.w);
    *(us8*)(wbf2 + (size_t)gid * 8) = o;
}

// ---------------------------------------------------------------------------
// k_main: L1-shared-B full-K design. 256 blocks x 256 thr = 4 waves;
// wave wm = 16 tokens x 128 cols x FULL K (64 steps of 32). All 4 waves walk
// the SAME rotated K-sequence -> per-step B window 8 KB x depth-3 = 24 KB
// fits L1: wave 0 misses to L2, waves 1-3 L1-hit. No K-combine.
// Inner step = R8/R12-verbatim: 10 asm loads (8 B + 2 X), depth-3 slots,
// WAITV(20/10/0), per-block K-rotation s0=(blk>>3)&63.
// ---------------------------------------------------------------------------
__global__ __launch_bounds__(256, 1) void k_main(const float* __restrict__ X,
                                                 const unsigned short* __restrict__ wbf2,
                                                 const float* __restrict__ noise,
                                                 float* __restrict__ sumraw,
                                                 float* __restrict__ sumsoft) {
    __shared__ float epf[TOKB * 68];  // weight[64][68] (17.4 KB)
    __shared__ float lsoft[NE];

    const int tid  = threadIdx.x;
    const int wid  = tid >> 6;
    const int lane = tid & 63;
    const int wm   = wid;             // token group (16 tokens), 4 waves
    const int lr   = lane & 15;
    const int lg   = lane >> 4;
    const int t0   = blockIdx.x * TOKB;
    const int s0   = (blockIdx.x >> 3) & 63;   // per-block K rotation

    if (tid < NE) lsoft[tid] = 0.f;

    const float* xp = X + (size_t)(t0 + wm * 16 + lr) * H + lg * 8;
    const unsigned short* bp0 = wbf2 + (size_t)lane * 8;

    f32x4 acc[8];
    #pragma unroll
    for (int i = 0; i < 8; ++i) acc[i] = (f32x4){0.f, 0.f, 0.f, 0.f};

    float4 xb[3][2];                  // X depth-3 (24 VGPR)
    us8    bb[3][8];                  // B depth-3 (96 VGPR)

    // issue rotated step sv into slot: 8 B loads then 2 X loads (10 VMEM)
    #define ISSUE(slot, sv)                                                  \
        do {                                                                 \
            const unsigned short* bA = bp0 + (size_t)(sv) * 4096;            \
            const unsigned short* bB = bA + 2048;                            \
            GLOAD_F4(bb[slot][0], bA, 0);                                    \
            GLOAD_F4(bb[slot][1], bA, 1024);                                 \
            GLOAD_F4(bb[slot][2], bA, 2048);                                 \
            GLOAD_F4(bb[slot][3], bA, 3072);                                 \
            GLOAD_F4(bb[slot][4], bB, 0);                                    \
            GLOAD_F4(bb[slot][5], bB, 1024);                                 \
            GLOAD_F4(bb[slot][6], bB, 2048);                                 \
            GLOAD_F4(bb[slot][7], bB, 3072);                                 \
            const float* xA = xp + (size_t)(sv) * 32;                        \
            GLOAD_F4(xb[slot][0], xA, 0);                                    \
            GLOAD_F4(xb[slot][1], xA, 16);                                   \
        } while (0)

    ISSUE(0, s0);
    ISSUE(1, (s0 + 1) & 63);
    ISSUE(2, (s0 + 2) & 63);

    #pragma unroll
    for (int j = 0; j < STEPS; ++j) {
        const int slot = j % 3;       // static after unroll
        if (j < STEPS - 2)       WAITV(20);   // step j's 10 oldest done
        else if (j == STEPS - 2) WAITV(10);
        else                     WAITV(0);

        float4 c0 = xb[slot][0], c1 = xb[slot][1];
        bf16x8 af;
        af[0] = (__bf16)c0.x; af[1] = (__bf16)c0.y;
        af[2] = (__bf16)c0.z; af[3] = (__bf16)c0.w;
        af[4] = (__bf16)c1.x; af[5] = (__bf16)c1.y;
        af[6] = (__bf16)c1.z; af[7] = (__bf16)c1.w;
        #pragma unroll
        for (int nb = 0; nb < 8; ++nb) {
            bf16x8 bfr = __builtin_bit_cast(bf16x8, bb[slot][nb]);
            acc[nb] = __builtin_amdgcn_mfma_f32_16x16x32_bf16(af, bfr, acc[nb], 0, 0, 0);
        }
        if (j + 3 < STEPS) ISSUE(slot, (s0 + j + 3) & 63);
    }
    #undef ISSUE

    // ---- gate: weight = logit_t + softplus(logit_n) * noise[e] (wave-local,
    // full K in acc -> no combine). C/D layout: expert col = lane&15 (+nb*16),
    // token row = wm*16 + (lane>>4)*4 + r.
    {
        float nz[4];
        #pragma unroll
        for (int nb = 0; nb < 4; ++nb) nz[nb] = noise[nb * 16 + lr];
        #pragma unroll
        for (int nb = 0; nb < 4; ++nb)
            #pragma unroll
            for (int r = 0; r < 4; ++r) {
                float lt  = acc[nb][r];
                float lnv = acc[nb + 4][r];
                float sp  = fmaxf(lnv, 0.f) + log1pf(expf(-fabsf(lnv)));
                epf[(wm * 16 + lg * 4 + r) * 68 + nb * 16 + lr] = lt + sp * nz[nb];
            }
    }
    __syncthreads();

    // ---- per-token top-8 + masked softmax (threads 0..63, one token each) ----
    if (tid < TOKB) {
        float tv[KTOP]; int ti[KTOP];
        #pragma unroll
        for (int q = 0; q < KTOP; ++q) { tv[q] = -INFINITY; ti[q] = 0; }
        for (int e = 0; e < NE; ++e) {
            float cv = epf[tid * 68 + e]; int ci = e;
            #pragma unroll
            for (int q = 0; q < KTOP; ++q) {
                if (cv > tv[q]) {
                    float t_ = tv[q]; int i_ = ti[q];
                    tv[q] = cv; ti[q] = ci;
                    cv = t_; ci = i_;
                }
            }
        }
        float m = tv[0], den = 0.f, pr[KTOP];
        #pragma unroll
        for (int q = 0; q < KTOP; ++q) { pr[q] = expf(tv[q] - m); den += pr[q]; }
        float inv = 1.f / den;
        #pragma unroll
        for (int q = 0; q < KTOP; ++q) atomicAdd(&lsoft[ti[q]], pr[q] * inv);
    }
    __syncthreads();

    // ---- per-expert sums -> global atomics (threads 0..63) ----
    if (tid < NE) {
        float s = 0.f;
        #pragma unroll
        for (int t = 0; t < TOKB; ++t) s += epf[t * 68 + tid];
        atomicAdd(&sumraw[tid], s);
        atomicAdd(&sumsoft[tid], lsoft[tid]);
    }
}

// ---------------------------------------------------------------------------
// k_final: mean top-8 + softmax -> out[0..15]; CV^2 -> out[16]
// ---------------------------------------------------------------------------
__global__ void k_final(const float* __restrict__ sumraw,
                        const float* __restrict__ sumsoft,
                        float* __restrict__ out) {
    if (threadIdx.x != 0 || blockIdx.x != 0) return;

    float mw[NE];
    for (int e = 0; e < NE; ++e) mw[e] = sumraw[e] * (1.f / (float)NTOK);

    float tv[KTOP]; int ti[KTOP];
    for (int q = 0; q < KTOP; ++q) { tv[q] = -INFINITY; ti[q] = 0; }
    for (int e = 0; e < NE; ++e) {
        float cv = mw[e]; int ci = e;
        for (int q = 0; q < KTOP; ++q) {
            if (cv > tv[q]) {
                float t_ = tv[q]; int i_ = ti[q];
                tv[q] = cv; ti[q] = ci;
                cv = t_; ci = i_;
            }
        }
    }
    float m = tv[0], den = 0.f, pr[KTOP];
    for (int q = 0; q < KTOP; ++q) { pr[q] = expf(tv[q] - m); den += pr[q]; }
    for (int q = 0; q < KTOP; ++q) {
        out[q] = pr[q] / den;
        out[KTOP + q] = (float)ti[q];
    }

    float s = 0.f;
    for (int e = 0; e < NE; ++e) s += sumsoft[e];
    float mean = s / (float)NE;
    float var = 0.f;
    for (int e = 0; e < NE; ++e) { float d = sumsoft[e] - mean; var += d * d; }
    var /= (float)(NE - 1);  // ddof=1
    out[16] = var / (mean * mean);
}

extern "C" void kernel_launch(void* const* d_in, const int* in_sizes, int n_in,
                              void* d_out, int out_size, void* d_ws, size_t ws_size,
                              hipStream_t stream) {
    (void)in_sizes; (void)n_in; (void)out_size; (void)ws_size;
    const float* x     = (const float*)d_in[0];
    const float* wt    = (const float*)d_in[1];
    const float* wn    = (const float*)d_in[2];
    const float* noise = (const float*)d_in[3];
    float* out = (float*)d_out;

    float* sumraw  = (float*)d_ws;                          // [64]
    float* sumsoft = sumraw + NE;                           // [64]
    unsigned short* wbf2 = (unsigned short*)(sumsoft + NE); // [128][2048] bf16 frag-linear

    k_prep<<<128, 256, 0, stream>>>(wt, wn, wbf2, sumraw);
    k_main<<<256, 256, 0, stream>>>(x, wbf2, noise, sumraw, sumsoft);
    k_final<<<1, 64, 0, stream>>>(sumraw, sumsoft, out);
}

// Round 15
// 99.685 us; speedup vs baseline: 1.3937x; 1.0212x over previous
//
#include <hip/hip_runtime.h>
#include <math.h>

#define H     2048
#define NE    64
#define KTOP  8
#define NTOK  16384
#define TOKB  64
#define STEPS 32                       // K-half (1024) / 32

typedef __attribute__((ext_vector_type(8))) __bf16 bf16x8;
typedef __attribute__((ext_vector_type(8))) unsigned short us8;
typedef __attribute__((ext_vector_type(4))) float f32x4;

__device__ __forceinline__ unsigned short f2bf(float f) {
    unsigned u = __builtin_bit_cast(unsigned, f);
    return (unsigned short)((u + 0x7FFFu + ((u >> 16) & 1u)) >> 16);  // RNE
}

// volatile asm global loads: compiler cannot sink/reorder/drain them.
#define GLOAD_F4(dst, ptr, OFF)                                        \
    asm volatile("global_load_dwordx4 %0, %1, off offset:%2"           \
                 : "=v"(dst) : "v"(ptr), "i"(OFF))
#define WAITV(N)                                                       \
    do { asm volatile("s_waitcnt vmcnt(%0)" :: "i"(N));                \
         __builtin_amdgcn_sched_barrier(0); } while (0)

// ---------------------------------------------------------------------------
// k_prep: W fp32 -> bf16, fragment-linear (R12 layout):
// wbf2[((k32*8 + nb)*64 + ln)*8 ..] = W[nb*16 + (ln&15)][k32*32 + (ln>>4)*8 ..+7]
// ---------------------------------------------------------------------------
__global__ __launch_bounds__(256) void k_prep(const float* __restrict__ Wt,
                                              const float* __restrict__ Wn,
                                              unsigned short* __restrict__ wbf2,
                                              float* __restrict__ sums) {
    const int gid = blockIdx.x * 256 + threadIdx.x;   // 32768 threads
    if (blockIdx.x == 0 && threadIdx.x < 128) sums[threadIdx.x] = 0.f;

    const int ln  = gid & 63;
    const int nb  = (gid >> 6) & 7;
    const int k32 = gid >> 9;
    const int row = nb * 16 + (ln & 15);
    const int col = k32 * 32 + (ln >> 4) * 8;
    const float* src = (row < NE) ? (Wt + (size_t)row * H + col)
                                  : (Wn + (size_t)(row - NE) * H + col);
    float4 v0 = *(const float4*)src;
    float4 v1 = *(const float4*)(src + 4);
    us8 o;
    o[0] = f2bf(v0.x); o[1] = f2bf(v0.y); o[2] = f2bf(v0.z); o[3] = f2bf(v0.w);
    o[4] = f2bf(v1.x); o[5] = f2bf(v1.y); o[6] = f2bf(v1.z); o[7] = f2bf(v1.w);
    *(us8*)(wbf2 + (size_t)gid * 8) = o;
}

// ---------------------------------------------------------------------------
// k_main: instruction-diet. 256 blocks x 256 thr = 4 waves (2 wm x 2 kp);
// wave = 32 tokens (2 M-frags) x 128 cols x K-half [kp*1024,+1024).
// 32 steps: 12 asm loads (8 B + 4 X) for 16 MFMA -> per-CU load-instr count
// 1536 vs R12's 2560. 256-thr/(256,1) launch bounds -> up to ~512 VGPR/thread,
// so the ~240-reg live set (acc 64 + bb 96 + xb 48) cannot spill asm dests
// (the R9 NaN mode). Depth-3 slots, WAITV(24/12/0), per-block K-rotation.
// Epilogue: 2-way kp-combine in LDS -> gate -> top8/softmax -> atomics.
// ---------------------------------------------------------------------------
__global__ __launch_bounds__(256, 1) void k_main(const float* __restrict__ X,
                                                 const unsigned short* __restrict__ wbf2,
                                                 const float* __restrict__ noise,
                                                 float* __restrict__ sumraw,
                                                 float* __restrict__ sumsoft) {
    __shared__ float cb[2][4096];     // kp=1 dump per wm (32 KB)
    __shared__ float epf[TOKB * 68];  // weight[64][68] (17.4 KB)
    __shared__ float lsoft[NE];

    const int tid  = threadIdx.x;
    const int wid  = tid >> 6;
    const int lane = tid & 63;
    const int wm   = wid & 1;         // token half (32 tokens)
    const int kp   = wid >> 1;        // K half
    const int lr   = lane & 15;
    const int lg   = lane >> 4;
    const int t0   = blockIdx.x * TOKB;
    const int s0   = (blockIdx.x >> 3) & 31;   // per-block K rotation

    if (tid < NE) lsoft[tid] = 0.f;

    const float* xp0 = X + (size_t)(t0 + wm * 32 + lr) * H + kp * 1024 + lg * 8;
    const float* xp1 = xp0 + (size_t)16 * H;
    const unsigned short* bp0 = wbf2 + (size_t)kp * 32 * 4096 + (size_t)lane * 8;

    f32x4 acc[2][8];
    #pragma unroll
    for (int m = 0; m < 2; ++m)
        #pragma unroll
        for (int i = 0; i < 8; ++i) acc[m][i] = (f32x4){0.f, 0.f, 0.f, 0.f};

    float4 xb[3][2][2];               // [slot][mf][16B-half]  48 VGPR
    us8    bb[3][8];                  // [slot][nb]            96 VGPR

    // one step: 8 B loads then 4 X loads (12 VMEM, fixed order)
    #define ISSUE(slot, sv)                                                  \
        do {                                                                 \
            const unsigned short* bA = bp0 + (size_t)(sv) * 4096;            \
            const unsigned short* bB = bA + 2048;                            \
            GLOAD_F4(bb[slot][0], bA, 0);                                    \
            GLOAD_F4(bb[slot][1], bA, 1024);                                 \
            GLOAD_F4(bb[slot][2], bA, 2048);                                 \
            GLOAD_F4(bb[slot][3], bA, 3072);                                 \
            GLOAD_F4(bb[slot][4], bB, 0);                                    \
            GLOAD_F4(bb[slot][5], bB, 1024);                                 \
            GLOAD_F4(bb[slot][6], bB, 2048);                                 \
            GLOAD_F4(bb[slot][7], bB, 3072);                                 \
            const float* xA0 = xp0 + (size_t)(sv) * 32;                      \
            const float* xA1 = xp1 + (size_t)(sv) * 32;                      \
            GLOAD_F4(xb[slot][0][0], xA0, 0);                                \
            GLOAD_F4(xb[slot][0][1], xA0, 16);                               \
            GLOAD_F4(xb[slot][1][0], xA1, 0);                                \
            GLOAD_F4(xb[slot][1][1], xA1, 16);                               \
        } while (0)

    ISSUE(0, s0);
    ISSUE(1, (s0 + 1) & 31);
    ISSUE(2, (s0 + 2) & 31);

    #pragma unroll
    for (int j = 0; j < STEPS; ++j) {
        const int slot = j % 3;       // static after unroll
        if (j < STEPS - 2)       WAITV(24);   // step j's 12 oldest done
        else if (j == STEPS - 2) WAITV(12);
        else                     WAITV(0);

        bf16x8 af0, af1;
        {
            float4 c0 = xb[slot][0][0], c1 = xb[slot][0][1];
            af0[0] = (__bf16)c0.x; af0[1] = (__bf16)c0.y;
            af0[2] = (__bf16)c0.z; af0[3] = (__bf16)c0.w;
            af0[4] = (__bf16)c1.x; af0[5] = (__bf16)c1.y;
            af0[6] = (__bf16)c1.z; af0[7] = (__bf16)c1.w;
            float4 d0 = xb[slot][1][0], d1 = xb[slot][1][1];
            af1[0] = (__bf16)d0.x; af1[1] = (__bf16)d0.y;
            af1[2] = (__bf16)d0.z; af1[3] = (__bf16)d0.w;
            af1[4] = (__bf16)d1.x; af1[5] = (__bf16)d1.y;
            af1[6] = (__bf16)d1.z; af1[7] = (__bf16)d1.w;
        }
        #pragma unroll
        for (int nb = 0; nb < 8; ++nb) {
            bf16x8 bfr = __builtin_bit_cast(bf16x8, bb[slot][nb]);
            acc[0][nb] = __builtin_amdgcn_mfma_f32_16x16x32_bf16(af0, bfr, acc[0][nb], 0, 0, 0);
            acc[1][nb] = __builtin_amdgcn_mfma_f32_16x16x32_bf16(af1, bfr, acc[1][nb], 0, 0, 0);
        }
        if (j + 3 < STEPS) ISSUE(slot, (s0 + j + 3) & 31);
    }
    #undef ISSUE

    // ---- 2-way kp combine (kp=1 dumps, kp=0 adds) ----
    if (kp == 1) {
        #pragma unroll
        for (int m = 0; m < 2; ++m)
            #pragma unroll
            for (int nb = 0; nb < 8; ++nb)
                #pragma unroll
                for (int r = 0; r < 4; ++r)
                    cb[wm][((m * 8 + nb) * 4 + r) * 64 + lane] = acc[m][nb][r];
    }
    __syncthreads();

    if (kp == 0) {
        #pragma unroll
        for (int m = 0; m < 2; ++m)
            #pragma unroll
            for (int nb = 0; nb < 8; ++nb)
                #pragma unroll
                for (int r = 0; r < 4; ++r)
                    acc[m][nb][r] += cb[wm][((m * 8 + nb) * 4 + r) * 64 + lane];
        float nz[4];
        #pragma unroll
        for (int nb = 0; nb < 4; ++nb) nz[nb] = noise[nb * 16 + lr];
        // gate: weight = logit_t + softplus(logit_n) * noise[e]
        // C/D layout: expert col = lane&15 (+nb*16), token row = wm*32+m*16+(lane>>4)*4+r
        #pragma unroll
        for (int m = 0; m < 2; ++m)
            #pragma unroll
            for (int nb = 0; nb < 4; ++nb)
                #pragma unroll
                for (int r = 0; r < 4; ++r) {
                    float lt  = acc[m][nb][r];
                    float lnv = acc[m][nb + 4][r];
                    float sp  = fmaxf(lnv, 0.f) + log1pf(expf(-fabsf(lnv)));
                    epf[(wm * 32 + m * 16 + lg * 4 + r) * 68 + nb * 16 + lr] = lt + sp * nz[nb];
                }
    }
    __syncthreads();

    // ---- per-token top-8 + masked softmax (threads 0..63, one token each) ----
    if (tid < TOKB) {
        float tv[KTOP]; int ti[KTOP];
        #pragma unroll
        for (int q = 0; q < KTOP; ++q) { tv[q] = -INFINITY; ti[q] = 0; }
        for (int e = 0; e < NE; ++e) {
            float cv = epf[tid * 68 + e]; int ci = e;
            #pragma unroll
            for (int q = 0; q < KTOP; ++q) {
                if (cv > tv[q]) {
                    float t_ = tv[q]; int i_ = ti[q];
                    tv[q] = cv; ti[q] = ci;
                    cv = t_; ci = i_;
                }
            }
        }
        float m = tv[0], den = 0.f, pr[KTOP];
        #pragma unroll
        for (int q = 0; q < KTOP; ++q) { pr[q] = expf(tv[q] - m); den += pr[q]; }
        float inv = 1.f / den;
        #pragma unroll
        for (int q = 0; q < KTOP; ++q) atomicAdd(&lsoft[ti[q]], pr[q] * inv);
    }
    __syncthreads();

    // ---- per-expert sums -> global atomics (threads 0..63) ----
    if (tid < NE) {
        float s = 0.f;
        #pragma unroll
        for (int t = 0; t < TOKB; ++t) s += epf[t * 68 + tid];
        atomicAdd(&sumraw[tid], s);
        atomicAdd(&sumsoft[tid], lsoft[tid]);
    }
}

// ---------------------------------------------------------------------------
// k_final: mean top-8 + softmax -> out[0..15]; CV^2 -> out[16]
// ---------------------------------------------------------------------------
__global__ void k_final(const float* __restrict__ sumraw,
                        const float* __restrict__ sumsoft,
                        float* __restrict__ out) {
    if (threadIdx.x != 0 || blockIdx.x != 0) return;

    float mw[NE];
    for (int e = 0; e < NE; ++e) mw[e] = sumraw[e] * (1.f / (float)NTOK);

    float tv[KTOP]; int ti[KTOP];
    for (int q = 0; q < KTOP; ++q) { tv[q] = -INFINITY; ti[q] = 0; }
    for (int e = 0; e < NE; ++e) {
        float cv = mw[e]; int ci = e;
        for (int q = 0; q < KTOP; ++q) {
            if (cv > tv[q]) {
                float t_ = tv[q]; int i_ = ti[q];
                tv[q] = cv; ti[q] = ci;
                cv = t_; ci = i_;
            }
        }
    }
    float m = tv[0], den = 0.f, pr[KTOP];
    for (int q = 0; q < KTOP; ++q) { pr[q] = expf(tv[q] - m); den += pr[q]; }
    for (int q = 0; q < KTOP; ++q) {
        out[q] = pr[q] / den;
        out[KTOP + q] = (float)ti[q];
    }

    float s = 0.f;
    for (int e = 0; e < NE; ++e) s += sumsoft[e];
    float mean = s / (float)NE;
    float var = 0.f;
    for (int e = 0; e < NE; ++e) { float d = sumsoft[e] - mean; var += d * d; }
    var /= (float)(NE - 1);  // ddof=1
    out[16] = var / (mean * mean);
}

extern "C" void kernel_launch(void* const* d_in, const int* in_sizes, int n_in,
                              void* d_out, int out_size, void* d_ws, size_t ws_size,
                              hipStream_t stream) {
    (void)in_sizes; (void)n_in; (void)out_size; (void)ws_size;
    const float* x     = (const float*)d_in[0];
    const float* wt    = (const float*)d_in[1];
    const float* wn    = (const float*)d_in[2];
    const float* noise = (const float*)d_in[3];
    float* out = (float*)d_out;

    float* sumraw  = (float*)d_ws;                          // [64]
    float* sumsoft = sumraw + NE;                           // [64]
    unsigned short* wbf2 = (unsigned short*)(sumsoft + NE); // [128][2048] bf16 frag-linear

    k_prep<<<128, 256, 0, stream>>>(wt, wn, wbf2, sumraw);
    k_main<<<256, 256, 0, stream>>>(x, wbf2, noise, sumraw, sumsoft);
    k_final<<<1, 64, 0, stream>>>(sumraw, sumsoft, out);
}